// Round 1
// baseline (161.394 us; speedup 1.0000x reference)
//
#include <hip/hip_runtime.h>
#include <hip/hip_bf16.h>
#include <stdint.h>
#include <math.h>

// Problem: x (B=4,L=2048,N=2048) fp32 @ W (N=2048,K=2048) ternary fp32, * scale[K],
// then per-row-of-K Poincare exp map + ball clamp. Output fp32 (8192 x 2048).
#define M_DIM 8192
#define K_DIM 2048   // reduction dim (N in reference)
#define N_DIM 2048   // output dim  (K in reference)

#define BM 128
#define BN 128
#define BK 64

typedef __attribute__((ext_vector_type(8))) short short8;
typedef __attribute__((ext_vector_type(4))) float f32x4;
typedef __attribute__((ext_vector_type(4))) float float4v;

__device__ __forceinline__ ushort f2bf(float f) {
    uint32_t u = __builtin_bit_cast(uint32_t, f);
    u = (u + 0x7fffu + ((u >> 16) & 1u)) >> 16;
    return (ushort)u;
}

// ---------------- prepass 1: W (K_DIM x N_DIM fp32) -> Wt (N_DIM x K_DIM bf16) ----------
__global__ __launch_bounds__(256) void transpose_w(const float* __restrict__ W,
                                                   ushort* __restrict__ Wt) {
    __shared__ float tile[32][33];
    const int tb = blockIdx.x;
    const int kb = (tb & 63) * 32;   // along k (rows of W); 2048/32 = 64
    const int nb = (tb >> 6) * 32;   // along n (cols of W)
    const int tx = threadIdx.x & 31;
    const int ty4 = (threadIdx.x >> 5) * 4;
#pragma unroll
    for (int i = 0; i < 4; i++)
        tile[ty4 + i][tx] = W[(size_t)(kb + ty4 + i) * N_DIM + nb + tx];
    __syncthreads();
#pragma unroll
    for (int i = 0; i < 4; i++)
        Wt[(size_t)(nb + ty4 + i) * K_DIM + kb + tx] = f2bf(tile[tx][ty4 + i]);
}

// ---------------- prepass 2: x fp32 -> bf16 ----------------
__global__ __launch_bounds__(256) void convert_x(const float* __restrict__ X,
                                                 ushort* __restrict__ Xb) {
    const size_t i = ((size_t)blockIdx.x * 256 + threadIdx.x) * 8;
    float4v a = *(const float4v*)&X[i];
    float4v b = *(const float4v*)&X[i + 4];
    short8 o;
    o[0] = (short)f2bf(a[0]); o[1] = (short)f2bf(a[1]);
    o[2] = (short)f2bf(a[2]); o[3] = (short)f2bf(a[3]);
    o[4] = (short)f2bf(b[0]); o[5] = (short)f2bf(b[1]);
    o[6] = (short)f2bf(b[2]); o[7] = (short)f2bf(b[3]);
    *(short8*)&Xb[i] = o;
}

// ---------------- GEMM: C = (Xb @ W) * scale, fp32 out ----------------
// Xb: [M][K] bf16 (k-contiguous), Wt: [N][K] bf16 (k-contiguous).
// 256 threads = 4 waves (2x2), each wave does a 64x64 subtile = 4x4 fragments of 16x16x32.
__global__ __launch_bounds__(256, 2) void gemm_kernel(const ushort* __restrict__ Xb,
                                                      const ushort* __restrict__ Wt,
                                                      const float* __restrict__ scale,
                                                      float* __restrict__ C) {
    // XOR-swizzled tiles: element (r, c) stored at [r*BK + (c ^ ((r&7)*8))]
    __shared__ __align__(16) ushort As[BM * BK];
    __shared__ __align__(16) ushort Bs[BN * BK];

    const int tid = threadIdx.x;
    const int wid = tid >> 6;
    const int lane = tid & 63;
    const int lrow = lane & 15;
    const int lkhi = (lane >> 4) * 8;   // 0,8,16,24
    const int swz = (lrow & 7) << 3;    // read-side XOR (elements)

    const int ntiles = N_DIM / BN;      // 16
    const int mt = blockIdx.x / ntiles;
    const int nt = blockIdx.x % ntiles;
    const int row0 = mt * BM;
    const int col0 = nt * BN;

    const int wr = (wid >> 1) * 64;
    const int wc = (wid & 1) * 64;

    f32x4 acc[4][4] = {};

    for (int kt = 0; kt < K_DIM / BK; ++kt) {
        const int k0 = kt * BK;
        // ---- stage A: 128x64 bf16, 1024 16B-chunks, 4 per thread ----
#pragma unroll
        for (int i = 0; i < 4; i++) {
            const int ch = tid + i * 256;
            const int r = ch >> 3;
            const int c = (ch & 7) * 8;
            short8 v = *(const short8*)&Xb[(size_t)(row0 + r) * K_DIM + k0 + c];
            *(short8*)&As[r * BK + (c ^ ((r & 7) * 8))] = v;
        }
        // ---- stage B (Wt rows) ----
#pragma unroll
        for (int i = 0; i < 4; i++) {
            const int ch = tid + i * 256;
            const int n = ch >> 3;
            const int c = (ch & 7) * 8;
            short8 v = *(const short8*)&Wt[(size_t)(col0 + n) * K_DIM + k0 + c];
            *(short8*)&Bs[n * BK + (c ^ ((n & 7) * 8))] = v;
        }
        __syncthreads();

#pragma unroll
        for (int kk = 0; kk < 2; kk++) {
            const int kA = kk * 32 + lkhi;
            short8 af[4], bf[4];
#pragma unroll
            for (int m = 0; m < 4; m++) {
                const int r = wr + m * 16 + lrow;
                af[m] = *(const short8*)&As[r * BK + (kA ^ swz)];
            }
#pragma unroll
            for (int n = 0; n < 4; n++) {
                const int r = wc + n * 16 + lrow;
                bf[n] = *(const short8*)&Bs[r * BK + (kA ^ swz)];
            }
#pragma unroll
            for (int m = 0; m < 4; m++)
#pragma unroll
                for (int n = 0; n < 4; n++)
                    acc[m][n] = __builtin_amdgcn_mfma_f32_16x16x32_bf16(af[m], bf[n], acc[m][n], 0, 0, 0);
        }
        __syncthreads();
    }

    // ---- epilogue: apply per-column scale, write fp32 ----
    const int crow0 = row0 + wr + (lane >> 4) * 4;
    const int ccol = col0 + wc + lrow;
#pragma unroll
    for (int n = 0; n < 4; n++) {
        const float sc = scale[ccol + n * 16];
#pragma unroll
        for (int m = 0; m < 4; m++) {
#pragma unroll
            for (int j = 0; j < 4; j++) {
                C[(size_t)(crow0 + m * 16 + j) * N_DIM + ccol + n * 16] = acc[m][n][j] * sc;
            }
        }
    }
}

// ---------------- epilogue: per-row Poincare exp map + clamp, in place ----------------
__global__ __launch_bounds__(256) void mobius_rows(float* __restrict__ C) {
    float* p = C + (size_t)blockIdx.x * N_DIM;
    const int t = threadIdx.x;
    float4v a = *(const float4v*)&p[t * 8];
    float4v b = *(const float4v*)&p[t * 8 + 4];
    float ss = a[0]*a[0] + a[1]*a[1] + a[2]*a[2] + a[3]*a[3]
             + b[0]*b[0] + b[1]*b[1] + b[2]*b[2] + b[3]*b[3];
#pragma unroll
    for (int off = 1; off < 64; off <<= 1) ss += __shfl_xor(ss, off);
    __shared__ float wsum[4];
    if ((t & 63) == 0) wsum[t >> 6] = ss;
    __syncthreads();
    const float tot = wsum[0] + wsum[1] + wsum[2] + wsum[3];
    // reference: v_norm = max(||v||, EPS); out *= tanh(v_norm)/(v_norm + EPS);
    //            o_norm = max(||out||, EPS); out *= min(0.99/o_norm, 1)
    const float vn = fmaxf(sqrtf(tot), 1e-7f);
    const float tf = tanhf(vn) / (vn + 1e-7f);
    const float on = fmaxf(tf * vn, 1e-7f);
    const float g = tf * fminf(0.99f / on, 1.0f);
#pragma unroll
    for (int j = 0; j < 4; j++) { a[j] *= g; b[j] *= g; }
    *(float4v*)&p[t * 8] = a;
    *(float4v*)&p[t * 8 + 4] = b;
}

extern "C" void kernel_launch(void* const* d_in, const int* in_sizes, int n_in,
                              void* d_out, int out_size, void* d_ws, size_t ws_size,
                              hipStream_t stream) {
    const float* x = (const float*)d_in[0];       // [8192][2048] fp32
    const float* w = (const float*)d_in[1];       // [2048][2048] fp32 (ternary values)
    const float* scale = (const float*)d_in[2];   // [2048] fp32
    float* out = (float*)d_out;                   // [8192][2048] fp32

    ushort* Wt = (ushort*)d_ws;                                   // 8 MB
    ushort* Xb = (ushort*)((char*)d_ws + (size_t)N_DIM * K_DIM * 2); // 32 MB

    transpose_w<<<dim3(64 * 64), dim3(256), 0, stream>>>(w, Wt);
    convert_x<<<dim3((M_DIM * K_DIM) / (8 * 256)), dim3(256), 0, stream>>>(x, Xb);
    gemm_kernel<<<dim3((M_DIM / BM) * (N_DIM / BN)), dim3(256), 0, stream>>>(Xb, Wt, scale, out);
    mobius_rows<<<dim3(M_DIM), dim3(256), 0, stream>>>(out);
}

// Round 2
// 132.440 us; speedup vs baseline: 1.2186x; 1.2186x over previous
//
#include <hip/hip_runtime.h>
#include <hip/hip_bf16.h>
#include <stdint.h>
#include <math.h>

// Problem: x (B=4,L=2048,N=2048) fp32 @ W (N=2048,K=2048) ternary fp32, * scale[K],
// then per-row-of-K Poincare exp map + ball clamp. Output fp32 (8192 x 2048).
#define M_DIM 8192
#define K_DIM 2048   // reduction dim (N in reference)
#define N_DIM 2048   // output dim  (K in reference)

#define BM 128
#define BN 128
#define BK 64

typedef __attribute__((ext_vector_type(8))) short short8;
typedef __attribute__((ext_vector_type(4))) float f32x4;
typedef __attribute__((ext_vector_type(4))) float float4v;

__device__ __forceinline__ ushort f2bf(float f) {
    uint32_t u = __builtin_bit_cast(uint32_t, f);
    u = (u + 0x7fffu + ((u >> 16) & 1u)) >> 16;
    return (ushort)u;
}

// direct global->LDS DMA, 16B per lane; LDS dest = wave-uniform base + lane*16
#define GLD16(gp, lp)                                                          \
    __builtin_amdgcn_global_load_lds(                                          \
        (const __attribute__((address_space(1))) void*)(gp),                   \
        (__attribute__((address_space(3))) void*)(lp), 16, 0, 0)

// ---------------- prepass 1: W (K_DIM x N_DIM fp32) -> Wt (N_DIM x K_DIM bf16) ----------
__global__ __launch_bounds__(256) void transpose_w(const float* __restrict__ W,
                                                   ushort* __restrict__ Wt) {
    __shared__ float tile[32][33];
    const int tb = blockIdx.x;
    const int kb = (tb & 63) * 32;   // along k (rows of W); 2048/32 = 64
    const int nb = (tb >> 6) * 32;   // along n (cols of W)
    const int tx = threadIdx.x & 31;
    const int ty4 = (threadIdx.x >> 5) * 4;
#pragma unroll
    for (int i = 0; i < 4; i++)
        tile[ty4 + i][tx] = W[(size_t)(kb + ty4 + i) * N_DIM + nb + tx];
    __syncthreads();
#pragma unroll
    for (int i = 0; i < 4; i++)
        Wt[(size_t)(nb + ty4 + i) * K_DIM + kb + tx] = f2bf(tile[tx][ty4 + i]);
}

// ---------------- prepass 2: x fp32 -> bf16 ----------------
__global__ __launch_bounds__(256) void convert_x(const float* __restrict__ X,
                                                 ushort* __restrict__ Xb) {
    const size_t i = ((size_t)blockIdx.x * 256 + threadIdx.x) * 8;
    float4v a = *(const float4v*)&X[i];
    float4v b = *(const float4v*)&X[i + 4];
    short8 o;
    o[0] = (short)f2bf(a[0]); o[1] = (short)f2bf(a[1]);
    o[2] = (short)f2bf(a[2]); o[3] = (short)f2bf(a[3]);
    o[4] = (short)f2bf(b[0]); o[5] = (short)f2bf(b[1]);
    o[6] = (short)f2bf(b[2]); o[7] = (short)f2bf(b[3]);
    *(short8*)&Xb[i] = o;
}

// ---------------- GEMM: C = (Xb @ W) * scale, fp32 out ----------------
// Xb: [M][K] bf16 (k-contiguous), Wt: [N][K] bf16 (k-contiguous).
// m97 structure: global_load_lds(16B) staging, 2 barriers/K-step, 128x128 tile.
// LDS layout: logical 16B-chunk (r, c8) stored at linear slot r*8 + (c8 ^ (r&7));
// achieved by pre-swizzling the per-lane GLOBAL source (linear LDS dest),
// and applying the same XOR on the ds_read side (both-sides rule).
__global__ __launch_bounds__(256) void gemm_kernel(const ushort* __restrict__ Xb,
                                                   const ushort* __restrict__ Wt,
                                                   const float* __restrict__ scale,
                                                   float* __restrict__ C) {
    __shared__ __align__(16) ushort As[BM * BK];   // 16 KB
    __shared__ __align__(16) ushort Bs[BN * BK];   // 16 KB

    const int tid = threadIdx.x;
    const int wid = tid >> 6;
    const int lane = tid & 63;
    const int lrow = lane & 15;
    const int lkhi = (lane >> 4) * 8;   // k sub-offset 0,8,16,24
    const int swz = (lrow & 7) << 3;    // read-side XOR (elements)

    const int ntiles = N_DIM / BN;      // 16
    const int mt = blockIdx.x / ntiles;
    const int nt = blockIdx.x % ntiles;
    const int row0 = mt * BM;
    const int col0 = nt * BN;

    const int wr = (wid >> 1) * 64;
    const int wc = (wid & 1) * 64;

    // staging source precompute: slot s = wid*256 + i*64 + lane covers the tile;
    // logical (r, c8): r = s>>3, c8 = (s&7) ^ (r&7)  (inverse of the read swizzle)
    size_t aoff[4], boff[4];
#pragma unroll
    for (int i = 0; i < 4; i++) {
        const int s = wid * 256 + i * 64 + lane;
        const int r = s >> 3;
        const int c8 = (s & 7) ^ (r & 7);
        aoff[i] = (size_t)(row0 + r) * K_DIM + c8 * 8;
        boff[i] = (size_t)(col0 + r) * K_DIM + c8 * 8;
    }

    f32x4 acc[4][4] = {};

    for (int kt = 0; kt < K_DIM / BK; ++kt) {
        const int k0 = kt * BK;
        // ---- stage A+B: 8 x global_load_lds_dwordx4 per thread-slot group ----
#pragma unroll
        for (int i = 0; i < 4; i++) {
            GLD16(Xb + aoff[i] + k0, As + (size_t)(wid * 256 + i * 64) * 8);
        }
#pragma unroll
        for (int i = 0; i < 4; i++) {
            GLD16(Wt + boff[i] + k0, Bs + (size_t)(wid * 256 + i * 64) * 8);
        }
        __syncthreads();   // drains vmcnt(0): tiles resident

#pragma unroll
        for (int kk = 0; kk < 2; kk++) {
            const int kA = kk * 32 + lkhi;
            short8 af[4], bf[4];
#pragma unroll
            for (int m = 0; m < 4; m++) {
                const int r = wr + m * 16 + lrow;
                af[m] = *(const short8*)&As[r * BK + (kA ^ swz)];
            }
#pragma unroll
            for (int n = 0; n < 4; n++) {
                const int r = wc + n * 16 + lrow;
                bf[n] = *(const short8*)&Bs[r * BK + (kA ^ swz)];
            }
#pragma unroll
            for (int m = 0; m < 4; m++)
#pragma unroll
                for (int n = 0; n < 4; n++)
                    acc[m][n] = __builtin_amdgcn_mfma_f32_16x16x32_bf16(af[m], bf[n], acc[m][n], 0, 0, 0);
        }
        __syncthreads();   // before next iter overwrites LDS
    }

    // ---- epilogue: apply per-column scale, write fp32 ----
    const int crow0 = row0 + wr + (lane >> 4) * 4;
    const int ccol = col0 + wc + lrow;
#pragma unroll
    for (int n = 0; n < 4; n++) {
        const float sc = scale[ccol + n * 16];
#pragma unroll
        for (int m = 0; m < 4; m++) {
#pragma unroll
            for (int j = 0; j < 4; j++) {
                C[(size_t)(crow0 + m * 16 + j) * N_DIM + ccol + n * 16] = acc[m][n][j] * sc;
            }
        }
    }
}

// ---------------- epilogue: per-row Poincare exp map + clamp, in place ----------------
__global__ __launch_bounds__(256) void mobius_rows(float* __restrict__ C) {
    float* p = C + (size_t)blockIdx.x * N_DIM;
    const int t = threadIdx.x;
    float4v a = *(const float4v*)&p[t * 8];
    float4v b = *(const float4v*)&p[t * 8 + 4];
    float ss = a[0]*a[0] + a[1]*a[1] + a[2]*a[2] + a[3]*a[3]
             + b[0]*b[0] + b[1]*b[1] + b[2]*b[2] + b[3]*b[3];
#pragma unroll
    for (int off = 1; off < 64; off <<= 1) ss += __shfl_xor(ss, off);
    __shared__ float wsum[4];
    if ((t & 63) == 0) wsum[t >> 6] = ss;
    __syncthreads();
    const float tot = wsum[0] + wsum[1] + wsum[2] + wsum[3];
    // reference: v_norm = max(||v||, EPS); out *= tanh(v_norm)/(v_norm + EPS);
    //            o_norm = max(||out||, EPS); out *= min(0.99/o_norm, 1)
    const float vn = fmaxf(sqrtf(tot), 1e-7f);
    const float tf = tanhf(vn) / (vn + 1e-7f);
    const float on = fmaxf(tf * vn, 1e-7f);
    const float g = tf * fminf(0.99f / on, 1.0f);
#pragma unroll
    for (int j = 0; j < 4; j++) { a[j] *= g; b[j] *= g; }
    *(float4v*)&p[t * 8] = a;
    *(float4v*)&p[t * 8 + 4] = b;
}

extern "C" void kernel_launch(void* const* d_in, const int* in_sizes, int n_in,
                              void* d_out, int out_size, void* d_ws, size_t ws_size,
                              hipStream_t stream) {
    const float* x = (const float*)d_in[0];       // [8192][2048] fp32
    const float* w = (const float*)d_in[1];       // [2048][2048] fp32 (ternary values)
    const float* scale = (const float*)d_in[2];   // [2048] fp32
    float* out = (float*)d_out;                   // [8192][2048] fp32

    ushort* Wt = (ushort*)d_ws;                                      // 8 MB
    ushort* Xb = (ushort*)((char*)d_ws + (size_t)N_DIM * K_DIM * 2); // 32 MB

    transpose_w<<<dim3(64 * 64), dim3(256), 0, stream>>>(w, Wt);
    convert_x<<<dim3((M_DIM * K_DIM) / (8 * 256)), dim3(256), 0, stream>>>(x, Xb);
    gemm_kernel<<<dim3((M_DIM / BM) * (N_DIM / BN)), dim3(256), 0, stream>>>(Xb, Wt, scale, out);
    mobius_rows<<<dim3(M_DIM), dim3(256), 0, stream>>>(out);
}

// Round 3
// 112.416 us; speedup vs baseline: 1.4357x; 1.1781x over previous
//
#include <hip/hip_runtime.h>
#include <hip/hip_bf16.h>
#include <stdint.h>
#include <math.h>

// Problem: x (B=4,L=2048,N=2048) fp32 @ W (N=2048,K=2048) ternary fp32, * scale[K],
// then per-row-of-K Poincare exp map + ball clamp. Output fp32 (8192 x 2048).
#define M_DIM 8192
#define K_DIM 2048   // reduction dim (N in reference)
#define N_DIM 2048   // output dim  (K in reference)

#define BM 256
#define BN 256
#define BK 64
#define NT (K_DIM / BK)   // 32 K-tiles

typedef __attribute__((ext_vector_type(8))) short short8;
typedef __attribute__((ext_vector_type(4))) float f32x4;
typedef __attribute__((ext_vector_type(4))) float float4v;

__device__ __forceinline__ ushort f2bf(float f) {
    uint32_t u = __builtin_bit_cast(uint32_t, f);
    u = (u + 0x7fffu + ((u >> 16) & 1u)) >> 16;
    return (ushort)u;
}

// direct global->LDS DMA, 16B per lane; LDS dest = wave-uniform base + lane*16
#define GLD16(gp, lp)                                                          \
    __builtin_amdgcn_global_load_lds(                                          \
        (const __attribute__((address_space(1))) void*)(gp),                   \
        (__attribute__((address_space(3))) void*)(lp), 16, 0, 0)

// raw barrier: no vmcnt/lgkmcnt drain (unlike __syncthreads); memory-clobber
// fences stop the compiler moving LDS/global ops across it.
#define BAR()                                                                  \
    do {                                                                       \
        asm volatile("" ::: "memory");                                         \
        __builtin_amdgcn_s_barrier();                                          \
        asm volatile("" ::: "memory");                                         \
    } while (0)

#define VMCNT(n) asm volatile("s_waitcnt vmcnt(" #n ")" ::: "memory")

// ---------------- prepass 1: W (K_DIM x N_DIM fp32) -> Wt (N_DIM x K_DIM bf16) ----------
__global__ __launch_bounds__(256) void transpose_w(const float* __restrict__ W,
                                                   ushort* __restrict__ Wt) {
    __shared__ float tile[32][33];
    const int tb = blockIdx.x;
    const int kb = (tb & 63) * 32;
    const int nb = (tb >> 6) * 32;
    const int tx = threadIdx.x & 31;
    const int ty4 = (threadIdx.x >> 5) * 4;
#pragma unroll
    for (int i = 0; i < 4; i++)
        tile[ty4 + i][tx] = W[(size_t)(kb + ty4 + i) * N_DIM + nb + tx];
    __syncthreads();
#pragma unroll
    for (int i = 0; i < 4; i++)
        Wt[(size_t)(nb + ty4 + i) * K_DIM + kb + tx] = f2bf(tile[tx][ty4 + i]);
}

// ---------------- prepass 2: x fp32 -> bf16 ----------------
__global__ __launch_bounds__(256) void convert_x(const float* __restrict__ X,
                                                 ushort* __restrict__ Xb) {
    const size_t i = ((size_t)blockIdx.x * 256 + threadIdx.x) * 8;
    float4v a = *(const float4v*)&X[i];
    float4v b = *(const float4v*)&X[i + 4];
    short8 o;
    o[0] = (short)f2bf(a[0]); o[1] = (short)f2bf(a[1]);
    o[2] = (short)f2bf(a[2]); o[3] = (short)f2bf(a[3]);
    o[4] = (short)f2bf(b[0]); o[5] = (short)f2bf(b[1]);
    o[6] = (short)f2bf(b[2]); o[7] = (short)f2bf(b[3]);
    *(short8*)&Xb[i] = o;
}

// ---------------- GEMM: C = (Xb @ W) * scale, fp32 out ----------------
// 256x256 tile, BK=64, 512 threads = 8 waves (2M x 4N), per-wave C = 128x64.
// 8-phase-per-2-K-tiles schedule (4 phases/K-tile):
//   p0: ds_read B(8)+A_m01(4), prefetch B0[t+1];  p1: ds_read A_m2..7(12), prefetch B1[t+1];
//   p2: prefetch A0[t+2];                         p3: prefetch A1[t+2], vmcnt(4).
// Each phase: [reads|prefetch] -> s_barrier -> setprio(1) 16 MFMA setprio(0) -> s_barrier.
// LDS: per matrix 4 half-slots (128 rows x 64 k each); tile t's halves in slots
// (2t)&3,(2t+1)&3. Tile t's reads finish at end of p1, so p2/p3 writes into its
// slots (for t+2) are race-free by barrier discipline. vmcnt never drains to 0
// mid-loop (counted, 2 half-tiles in flight).
__global__ __launch_bounds__(512, 1) void gemm_kernel(const ushort* __restrict__ Xb,
                                                      const ushort* __restrict__ Wt,
                                                      const float* __restrict__ scale,
                                                      float* __restrict__ C) {
    __shared__ __align__(16) ushort lds[65536];   // 128 KiB: A slots [0,32768), B slots [32768,65536)

    const int tid = threadIdx.x;
    const int w = tid >> 6;            // wave 0..7
    const int lane = tid & 63;
    const int lrow = lane & 15;
    const int khi3 = lane >> 4;        // 0..3 (k chunk sub-index)
    const int rswz = lrow & 7;         // read-side XOR (chunk units)

    // XCD-chunked bijective swizzle (nwg=256, 8 XCDs): XCD x gets M-stripe [4x,4x+4) x all nt
    const int bid = blockIdx.x;
    const int wg = (bid & 7) * 32 + (bid >> 3);
    const int mt = wg >> 3;            // 0..31
    const int nt = wg & 7;             // 0..7
    const int row0 = mt * BM;
    const int col0 = nt * BN;

    const int wr = (w >> 2) * 128;     // wave M offset in tile
    const int wc = (w & 3) * 64;       // wave N offset in tile
    const int whalfA = w >> 2;         // which A half this wave reads
    const int whalfB = (w & 3) >> 1;   // which B half this wave reads
    const int wrB = (w & 1) * 64;      // row offset within B half

    // staging chunk geometry: thread covers chunks q = (i*8+w)*64 + lane, i=0,1
    // logical (r, c8src): r=q>>3, c8src=(q&7)^(r&7)  (inverse of read swizzle)
    int r_[2], c8_[2];
#pragma unroll
    for (int i = 0; i < 2; ++i) {
        const int q = (i * 8 + w) * 64 + lane;
        r_[i] = q >> 3;
        c8_[i] = (q & 7) ^ (r_[i] & 7);
    }

    auto stage2 = [&](const ushort* sb, int ldsbase) {
        GLD16(sb + (size_t)r_[0] * K_DIM + c8_[0] * 8, lds + ldsbase + (0 * 8 + w) * 512);
        GLD16(sb + (size_t)r_[1] * K_DIM + c8_[1] * 8, lds + ldsbase + (1 * 8 + w) * 512);
    };

#define RD_A(m, kk, base) (*(const short8*)&lds[(base) + ((m) * 16 + lrow) * 64 + ((((kk) * 4 + khi3) ^ rswz) * 8)])
#define RD_B(n, kk, base) (*(const short8*)&lds[(base) + (wrB + (n) * 16 + lrow) * 64 + ((((kk) * 4 + khi3) ^ rswz) * 8)])

    f32x4 acc[8][4] = {};
    short8 af[8][2], bf[4][2];

    const ushort* Asrc0 = Xb + (size_t)row0 * K_DIM;
    const ushort* Asrc1 = Xb + (size_t)(row0 + 128) * K_DIM;
    const ushort* Bsrc0 = Wt + (size_t)col0 * K_DIM;
    const ushort* Bsrc1 = Wt + (size_t)(col0 + 128) * K_DIM;

    // ---- prologue: stage h=0..5 = {A0,A1,B0,B1}[t0], {A0,A1}[t1] (12 loads) ----
    stage2(Asrc0, 0 * 8192);
    stage2(Asrc1, 1 * 8192);
    stage2(Bsrc0, 32768 + 0 * 8192);
    stage2(Bsrc1, 32768 + 1 * 8192);
    stage2(Asrc0 + BK, 2 * 8192);
    stage2(Asrc1 + BK, 3 * 8192);
    VMCNT(4);   // tile 0 fully landed; tile 1's A halves may be in flight
    BAR();

#define MFMA_PHASE(m0)                                                                              \
    do {                                                                                            \
        __builtin_amdgcn_s_setprio(1);                                                              \
        _Pragma("unroll") for (int kk = 0; kk < 2; ++kk) {                                          \
            _Pragma("unroll") for (int n = 0; n < 4; ++n) {                                         \
                acc[m0][n] = __builtin_amdgcn_mfma_f32_16x16x32_bf16(af[m0][kk], bf[n][kk], acc[m0][n], 0, 0, 0);         \
                acc[m0 + 1][n] = __builtin_amdgcn_mfma_f32_16x16x32_bf16(af[m0 + 1][kk], bf[n][kk], acc[m0 + 1][n], 0, 0, 0); \
            }                                                                                       \
        }                                                                                           \
        __builtin_amdgcn_s_setprio(0);                                                              \
    } while (0)

    for (int t = 0; t < NT; ++t) {
        const int abase = ((2 * t + whalfA) & 3) * 8192;
        const int bbase = 32768 + ((2 * t + whalfB) & 3) * 8192;

        // ---- phase 0: read B all + A m0,m1; prefetch B0[t+1] ----
#pragma unroll
        for (int kk = 0; kk < 2; ++kk) {
#pragma unroll
            for (int n = 0; n < 4; ++n) bf[n][kk] = RD_B(n, kk, bbase);
            af[0][kk] = RD_A(0, kk, abase);
            af[1][kk] = RD_A(1, kk, abase);
        }
        if (t + 1 < NT) stage2(Bsrc0 + (t + 1) * BK, 32768 + ((2 * (t + 1)) & 3) * 8192);
        BAR();
        MFMA_PHASE(0);
        BAR();

        // ---- phase 1: read A m2..7; prefetch B1[t+1] ----
#pragma unroll
        for (int kk = 0; kk < 2; ++kk) {
#pragma unroll
            for (int m = 2; m < 8; ++m) af[m][kk] = RD_A(m, kk, abase);
        }
        if (t + 1 < NT) stage2(Bsrc1 + (t + 1) * BK, 32768 + ((2 * (t + 1) + 1) & 3) * 8192);
        BAR();
        MFMA_PHASE(2);
        BAR();
        // tile t's LDS reads all complete here -> its slots are reusable

        // ---- phase 2: prefetch A0[t+2] (into tile t's A0 slot) ----
        if (t + 2 < NT) stage2(Asrc0 + (t + 2) * BK, ((2 * (t + 2)) & 3) * 8192);
        BAR();
        MFMA_PHASE(4);
        BAR();

        // ---- phase 3: prefetch A1[t+2]; counted vmcnt ----
        if (t + 2 < NT) stage2(Asrc1 + (t + 2) * BK, ((2 * (t + 2) + 1) & 3) * 8192);
        if (t < NT - 2) { VMCNT(4); } else { VMCNT(0); }   // tail: drain so last tile is resident
        BAR();
        MFMA_PHASE(6);
        BAR();
    }

    // ---- epilogue: apply per-column scale, write fp32 ----
    const int crow0 = row0 + wr + (lane >> 4) * 4;
    const int ccol = col0 + wc + lrow;
#pragma unroll
    for (int n = 0; n < 4; ++n) {
        const float sc = scale[ccol + n * 16];
#pragma unroll
        for (int m = 0; m < 8; ++m) {
#pragma unroll
            for (int j = 0; j < 4; ++j) {
                C[(size_t)(crow0 + m * 16 + j) * N_DIM + ccol + n * 16] = acc[m][n][j] * sc;
            }
        }
    }
#undef RD_A
#undef RD_B
#undef MFMA_PHASE
}

// ---------------- epilogue: per-row Poincare exp map + clamp, in place ----------------
__global__ __launch_bounds__(256) void mobius_rows(float* __restrict__ C) {
    float* p = C + (size_t)blockIdx.x * N_DIM;
    const int t = threadIdx.x;
    float4v a = *(const float4v*)&p[t * 8];
    float4v b = *(const float4v*)&p[t * 8 + 4];
    float ss = a[0]*a[0] + a[1]*a[1] + a[2]*a[2] + a[3]*a[3]
             + b[0]*b[0] + b[1]*b[1] + b[2]*b[2] + b[3]*b[3];
#pragma unroll
    for (int off = 1; off < 64; off <<= 1) ss += __shfl_xor(ss, off);
    __shared__ float wsum[4];
    if ((t & 63) == 0) wsum[t >> 6] = ss;
    __syncthreads();
    const float tot = wsum[0] + wsum[1] + wsum[2] + wsum[3];
    const float vn = fmaxf(sqrtf(tot), 1e-7f);
    const float tf = tanhf(vn) / (vn + 1e-7f);
    const float on = fmaxf(tf * vn, 1e-7f);
    const float g = tf * fminf(0.99f / on, 1.0f);
#pragma unroll
    for (int j = 0; j < 4; j++) { a[j] *= g; b[j] *= g; }
    *(float4v*)&p[t * 8] = a;
    *(float4v*)&p[t * 8 + 4] = b;
}

extern "C" void kernel_launch(void* const* d_in, const int* in_sizes, int n_in,
                              void* d_out, int out_size, void* d_ws, size_t ws_size,
                              hipStream_t stream) {
    const float* x = (const float*)d_in[0];
    const float* w = (const float*)d_in[1];
    const float* scale = (const float*)d_in[2];
    float* out = (float*)d_out;

    ushort* Wt = (ushort*)d_ws;                                      // 8 MB
    ushort* Xb = (ushort*)((char*)d_ws + (size_t)N_DIM * K_DIM * 2); // 32 MB

    transpose_w<<<dim3(64 * 64), dim3(256), 0, stream>>>(w, Wt);
    convert_x<<<dim3((M_DIM * K_DIM) / (8 * 256)), dim3(256), 0, stream>>>(x, Xb);
    gemm_kernel<<<dim3((M_DIM / BM) * (N_DIM / BN)), dim3(512), 0, stream>>>(Xb, Wt, scale, out);
    mobius_rows<<<dim3(M_DIM), dim3(256), 0, stream>>>(out);
}